// Round 1
// baseline (280.911 us; speedup 1.0000x reference)
//
#include <hip/hip_runtime.h>

// Problem constants (from reference)
#define BB 4
#define PP 12000
#define CC 64
#define HH 512
#define WW 512

// Kernel 1: winner[b*H*W + y*W + x] = max p among pillars hitting that cell.
// Winner buffer pre-initialized to -1 (0xFF memset). Last-write-wins in p order
// == max p, matching XLA CPU scatter-set semantics with duplicate indices.
__global__ void __launch_bounds__(256) winner_scatter(
    const int* __restrict__ coords, int* __restrict__ winner) {
    int tid = blockIdx.x * blockDim.x + threadIdx.x;
    if (tid >= BB * PP) return;
    int4 c4 = ((const int4*)coords)[tid];  // (batch, y, x, z)
    int y = c4.y;
    int x = c4.z;
    if (x >= 0 && x < WW && y >= 0 && y < HH) {
        int b = tid / PP;
        int p = tid - b * PP;
        atomicMax(&winner[(b * HH + y) * WW + x], p);
    }
}

// Kernel 2: gather-style fill. One thread per 4 x-contiguous cells; for each
// channel c, build a float4 and store coalesced (16 B/lane -> 1 KB/wave).
// Cells with no winner write zeros (the common case, ~95%).
__global__ void __launch_bounds__(256) fill_out(
    const float* __restrict__ feat, const int* __restrict__ winner,
    float* __restrict__ out) {
    int tid = blockIdx.x * blockDim.x + threadIdx.x;  // over B*H*W/4 = 262144
    int x4   = tid & (WW / 4 - 1);   // 0..127
    int rest = tid >> 7;             // b*H + y
    int y = rest & (HH - 1);
    int b = rest >> 9;

    int cell = (b * HH + y) * WW + x4 * 4;
    int4 w4 = *(const int4*)(winner + cell);

    const float* fbase = feat + (size_t)b * PP * CC;
    float* obase = out + ((size_t)(b * CC) * HH + y) * WW + x4 * 4;

#pragma unroll 8
    for (int c = 0; c < CC; ++c) {
        float4 v;
        v.x = (w4.x >= 0) ? fbase[(size_t)w4.x * CC + c] : 0.0f;
        v.y = (w4.y >= 0) ? fbase[(size_t)w4.y * CC + c] : 0.0f;
        v.z = (w4.z >= 0) ? fbase[(size_t)w4.z * CC + c] : 0.0f;
        v.w = (w4.w >= 0) ? fbase[(size_t)w4.w * CC + c] : 0.0f;
        *(float4*)(obase + (size_t)c * HH * WW) = v;
    }
}

extern "C" void kernel_launch(void* const* d_in, const int* in_sizes, int n_in,
                              void* d_out, int out_size, void* d_ws, size_t ws_size,
                              hipStream_t stream) {
    const float* feat  = (const float*)d_in[0];   // [B, P, C] fp32
    const int*   coords = (const int*)d_in[1];    // [B, P, 4] int32
    float* out = (float*)d_out;                   // [B, C, H, W] fp32
    int* winner = (int*)d_ws;                     // [B, H, W] int32 (4 MB)

    // Init winner map to -1 (0xFF bytes). d_ws is poisoned each call, so this
    // must run every launch. Graph-capture-safe (memset node).
    hipMemsetAsync(winner, 0xFF, (size_t)BB * HH * WW * sizeof(int), stream);

    // Resolve duplicates: winner = max pillar index per cell.
    {
        int n = BB * PP;
        winner_scatter<<<(n + 255) / 256, 256, 0, stream>>>(coords, winner);
    }

    // Fill the full canvas (zeros + gathered features), coalesced float4 stores.
    {
        int n = BB * HH * WW / 4;
        fill_out<<<(n + 255) / 256, 256, 0, stream>>>(feat, winner, out);
    }
}